// Round 1
// baseline (1057.274 us; speedup 1.0000x reference)
//
#include <hip/hip_runtime.h>
#include <math.h>

#define B_   4096
#define T_   1024
#define FEAT 30
#define HID  64
#define DK   32
#define NC   4

// ---------------------------------------------------------------------------
// Kernel A: encoder conv(3->64, K=3, VALID) + ReLU + mean over 1022 positions
// One block per batch element. lane = output channel (64), wave = t-range.
// All lanes of a wave read the SAME LDS window (broadcast), weights in regs.
// ---------------------------------------------------------------------------
__global__ __launch_bounds__(256) void encode_kernel(
    const float* __restrict__ S, const float* __restrict__ Wc,
    const float* __restrict__ bc, float* __restrict__ hout)
{
    __shared__ __align__(16) float xs[3072 + 8];
    __shared__ float partial[4][64];
    const int b = blockIdx.x;
    const int tid = threadIdx.x;
    const int lane = tid & 63;
    const int wv = tid >> 6;

    // stage S[b] : [1024][3] floats, coalesced float4
    {
        const float4* src = (const float4*)(S + (size_t)b * 3072);
        float4* dst = (float4*)xs;
        for (int i = tid; i < 768; i += 256) dst[i] = src[i];
        if (tid < 8) xs[3072 + tid] = 0.f;
    }
    // per-lane weights: channel o = lane, W[o][i][k], j = i*3+k
    float w[9];
    #pragma unroll
    for (int j = 0; j < 9; ++j) w[j] = Wc[lane * 9 + j];
    const float bias = bc[lane];
    __syncthreads();

    float acc = 0.f;
    const int tbase = wv * 256;
    #pragma unroll 1
    for (int j = 0; j < 64; ++j) {
        const int t0 = tbase + 4 * j;           // multiple of 4 -> 16B aligned
        const float* xp = xs + 3 * t0;          // window: xs[3t0 .. 3t0+17]
        float x[18];
        #pragma unroll
        for (int q = 0; q < 4; ++q) {
            float4 v = *(const float4*)(xp + 4 * q);
            x[4*q+0] = v.x; x[4*q+1] = v.y; x[4*q+2] = v.z; x[4*q+3] = v.w;
        }
        x[16] = xp[16]; x[17] = xp[17];
        if (t0 + 3 < 1022) {                    // fully valid chunk (uniform)
            #pragma unroll
            for (int p = 0; p < 4; ++p) {
                float s = bias;
                #pragma unroll
                for (int i = 0; i < 3; ++i)
                    #pragma unroll
                    for (int k = 0; k < 3; ++k)
                        s = fmaf(w[i*3+k], x[3*(p+k)+i], s);
                acc += fmaxf(s, 0.f);
            }
        } else {
            #pragma unroll
            for (int p = 0; p < 4; ++p) {
                if (t0 + p < 1022) {
                    float s = bias;
                    #pragma unroll
                    for (int i = 0; i < 3; ++i)
                        #pragma unroll
                        for (int k = 0; k < 3; ++k)
                            s = fmaf(w[i*3+k], x[3*(p+k)+i], s);
                    acc += fmaxf(s, 0.f);
                }
            }
        }
    }
    partial[wv][lane] = acc;
    __syncthreads();
    if (tid < 64) {
        float h = (partial[0][tid] + partial[1][tid] +
                   partial[2][tid] + partial[3][tid]) * (1.0f / 1022.0f);
        hout[(size_t)b * 64 + tid] = h;
    }
}

// ---------------------------------------------------------------------------
// Kernel B: physical model per batch element:
//   conv(3->64,K=5) -> maxpool4 -> conv(64->30,K=5) -> maxpool4 -> mean
// Phase 1: lane=channel, fused conv+pool into LDS p1[64][260].
// Phase 2: lane=t2 (251 outputs, 248 used), acc[30] in VGPRs; W2 indices are
// wave-uniform -> scalar loads. Pool+mean via shuffle reductions.
// ---------------------------------------------------------------------------
#define P1S 260
__global__ __launch_bounds__(256) void phys_kernel(
    const float* __restrict__ S, const float* __restrict__ W1,
    const float* __restrict__ b1, const float* __restrict__ W2,
    const float* __restrict__ b2, float* __restrict__ y30)
{
    __shared__ __align__(16) float xs[3072];
    __shared__ __align__(16) float p1[64 * P1S];
    __shared__ float ypart[4][32];
    const int b = blockIdx.x;
    const int tid = threadIdx.x;
    const int lane = tid & 63;
    const int wv = tid >> 6;

    {
        const float4* src = (const float4*)(S + (size_t)b * 3072);
        float4* dst = (float4*)xs;
        for (int i = tid; i < 768; i += 256) dst[i] = src[i];
    }
    // zero the pad columns tp = 255..259 (read by out-of-range lanes)
    for (int i = tid; i < 64 * 5; i += 256) {
        int r = i / 5, c = 255 + (i % 5);
        p1[r * P1S + c] = 0.f;
    }
    // phase-1 weights: channel = lane, W1[o][i][k], j = i*5+k
    float w1[15];
    #pragma unroll
    for (int j = 0; j < 15; ++j) w1[j] = W1[lane * 15 + j];
    const float bia1 = b1[lane];
    __syncthreads();

    // ---- phase 1: conv1 + maxpool4 -> p1[lane][tp], tp in 0..254
    #pragma unroll 1
    for (int tp = wv; tp < 255; tp += 4) {
        const float* xp = xs + 12 * tp;         // 24 floats, 16B aligned
        float x[24];
        #pragma unroll
        for (int q = 0; q < 6; ++q) {
            float4 v = *(const float4*)(xp + 4 * q);
            x[4*q+0] = v.x; x[4*q+1] = v.y; x[4*q+2] = v.z; x[4*q+3] = v.w;
        }
        float m = -INFINITY;
        #pragma unroll
        for (int p = 0; p < 4; ++p) {
            float s = 0.f;
            #pragma unroll
            for (int i = 0; i < 3; ++i)
                #pragma unroll
                for (int k = 0; k < 5; ++k)
                    s = fmaf(w1[i*5+k], x[3*(p+k)+i], s);
            m = fmaxf(m, s);
        }
        p1[lane * P1S + tp] = m + bia1;         // bias commutes with max
    }
    __syncthreads();

    // ---- phase 2: conv2 (K of 320) at t2 = tid; acc[f] for 30 out channels
    float acc[30];
    #pragma unroll
    for (int f = 0; f < 30; ++f) acc[f] = 0.f;
    const int t2 = tid;
    #pragma unroll 1
    for (int i = 0; i < 64; ++i) {
        const float* pr = p1 + i * P1S + t2;
        float x0 = pr[0], x1 = pr[1], x2 = pr[2], x3 = pr[3], x4 = pr[4];
        const float* wp = W2 + i * 5;           // wave-uniform -> s_load
        #pragma unroll
        for (int f = 0; f < 30; ++f) {
            const float* wf = wp + f * 320;
            float a = acc[f];
            a = fmaf(wf[0], x0, a);
            a = fmaf(wf[1], x1, a);
            a = fmaf(wf[2], x2, a);
            a = fmaf(wf[3], x3, a);
            a = fmaf(wf[4], x4, a);
            acc[f] = a;
        }
    }
    // ---- maxpool4 over t2 (windows 0..61 <-> t2 0..247) + mean
    const bool valid = (t2 < 248);
    #pragma unroll 1
    for (int f = 0; f < 30; ++f) {
        float v = acc[f];
        v = fmaxf(v, __shfl_xor(v, 1));
        v = fmaxf(v, __shfl_xor(v, 2));
        v = ((lane & 3) == 0 && valid) ? v : 0.f;
        v += __shfl_xor(v, 4);
        v += __shfl_xor(v, 8);
        v += __shfl_xor(v, 16);
        v += __shfl_xor(v, 32);
        if (lane == 0) ypart[wv][f] = v;
    }
    __syncthreads();
    if (tid < 30) {
        float y = (ypart[0][tid] + ypart[1][tid] +
                   ypart[2][tid] + ypart[3][tid]) * (1.0f / 62.0f) + b2[tid];
        y30[(size_t)b * 30 + tid] = y;
    }
}

// ---------------------------------------------------------------------------
// Kernel C: heads + LSE soft-OR fusion + masked 4-token attention. 1 wave/b.
// ---------------------------------------------------------------------------
__global__ __launch_bounds__(64) void head_kernel(
    const int* __restrict__ pairs,
    const float* __restrict__ hv_g, const float* __restrict__ hp_g,
    const float* __restrict__ y30_g,
    const float* __restrict__ Ws_v, const float* __restrict__ bs_v,
    const float* __restrict__ Wd_v, const float* __restrict__ bd_v,
    const float* __restrict__ Ws_p, const float* __restrict__ bs_p,
    const float* __restrict__ Wd_p, const float* __restrict__ bd_p,
    const float* __restrict__ Wsp, const float* __restrict__ bsp,
    const float* __restrict__ Wa,  const float* __restrict__ ba,
    const float* __restrict__ Wf,  const float* __restrict__ bf,
    float* __restrict__ out)
{
    __shared__ float hv[64], hp[64];
    __shared__ float s0v[32], s0p[32];
    __shared__ float f4[4][32];      // attn_in tokens: fp_d, feat_avg, y30, fv_d
    __shared__ float qk[4][192];
    __shared__ float qm[32];
    __shared__ float lg[4][4];
    __shared__ float wsm[4][4];
    __shared__ float ffl[4][32];
    const int b = blockIdx.x;
    const int lane = threadIdx.x;
    const int pf = pairs[b];

    hv[lane] = hv_g[(size_t)b * 64 + lane];
    hp[lane] = hp_g[(size_t)b * 64 + lane];
    __syncthreads();

    if (lane < 30) {
        float a_s = bs_v[lane], a_d = bd_v[lane];
        float p_s = bs_p[lane], p_d = bd_p[lane];
        for (int k = 0; k < 64; ++k) {
            float h = hv[k], g = hp[k];
            a_s = fmaf(h, Ws_v[k*30 + lane], a_s);
            a_d = fmaf(h, Wd_v[k*30 + lane], a_d);
            p_s = fmaf(g, Ws_p[k*30 + lane], p_s);
            p_d = fmaf(g, Wd_p[k*30 + lane], p_d);
        }
        s0v[lane] = a_s;
        s0p[lane] = p_s;
        f4[3][lane] = a_d;                       // fv_d
        f4[0][lane] = p_d;                       // fp_d
        f4[2][lane] = y30_g[(size_t)b * 30 + lane];
    }
    __syncthreads();

    if (lane < 30) {
        float v_s = bsp[lane], p_s = bsp[lane];
        for (int j = 0; j < 30; ++j) {
            float wj = Wsp[j*30 + lane];
            v_s = fmaf(s0v[j], wj, v_s);
            p_s = fmaf(s0p[j], wj, p_s);
        }
        // logsumexp soft-OR
        float h1 = v_s, h2 = p_s, h12 = h1 + h2;
        float m1 = fmaxf(h12, fmaxf(h1, h2));
        float lse1 = m1 + logf(2.f*expf(h12 - m1) + expf(h1 - m1) + expf(h2 - m1));
        float m2 = fmaxf(0.f, fmaxf(h1, h2));
        float lse2 = m2 + logf(2.f*expf(-m2) + expf(h1 - m2) + expf(h2 - m2));
        f4[1][lane] = pf ? (lse1 - lse2) : h2;   // feat_avg
    }
    __syncthreads();

    // qkvs = attn_in @ Wa + ba : [4][192]
    #pragma unroll 1
    for (int t = 0; t < 4; ++t) {
        #pragma unroll 1
        for (int c0 = 0; c0 < 3; ++c0) {
            int c = c0 * 64 + lane;
            float a = ba[c];
            for (int j = 0; j < 30; ++j)
                a = fmaf(f4[t][j], Wa[j*192 + c], a);
            qk[t][c] = a;
        }
    }
    __syncthreads();

    if (lane < 32) {
        float q0 = qk[0][lane], q1 = qk[1][lane], q2 = qk[2][lane], q3 = qk[3][lane];
        qm[lane] = pf ? (q0 + q1 + q2 + q3) * 0.25f
                      : (q0 + q1 + q2) * (1.f / 3.f);
    }
    __syncthreads();

    if (lane < 16) {
        int n = lane >> 2, t = lane & 3;
        float a = 0.f;
        const float* kp = &qk[t][64 + 32*n];
        for (int d = 0; d < 32; ++d) a = fmaf(kp[d], qm[d], a);
        a *= 0.17677669529663687f;               // 1/sqrt(32)
        if (t == 3 && pf == 0) a = -INFINITY;
        lg[n][t] = a;
    }
    __syncthreads();

    if (lane < 4) {
        float l0 = lg[lane][0], l1 = lg[lane][1], l2 = lg[lane][2], l3 = lg[lane][3];
        float m = fmaxf(fmaxf(l0, l1), fmaxf(l2, l3));
        float e0 = expf(l0 - m), e1 = expf(l1 - m), e2 = expf(l2 - m);
        float e3 = expf(l3 - m);                 // exp(-inf)=0 when masked
        float s = e0 + e1 + e2 + e3;
        wsm[lane][0] = e0 / s; wsm[lane][1] = e1 / s;
        wsm[lane][2] = e2 / s; wsm[lane][3] = e3 / s;
    }
    __syncthreads();

    #pragma unroll
    for (int r = 0; r < 2; ++r) {
        int n = (lane >> 5) + 2 * r, d = lane & 31;
        float a = 0.f;
        #pragma unroll
        for (int t = 0; t < 4; ++t) a = fmaf(wsm[n][t], qk[t][32 + d], a);
        ffl[n][d] = a;
    }
    __syncthreads();

    if (lane < 4) {
        float a = bf[lane];
        for (int d = 0; d < 32; ++d) a = fmaf(ffl[lane][d], Wf[d*4 + lane], a);
        out[(size_t)b * 4 + lane] = a;
    }
}

// ---------------------------------------------------------------------------
extern "C" void kernel_launch(void* const* d_in, const int* in_sizes, int n_in,
                              void* d_out, int out_size, void* d_ws, size_t ws_size,
                              hipStream_t stream)
{
    const int*   pairs = (const int*)  d_in[0];
    const float* S_V   = (const float*)d_in[1];
    const float* S_P   = (const float*)d_in[2];
    const float* S_P1  = (const float*)d_in[3];
    const float* Wc_v  = (const float*)d_in[4];
    const float* bc_v  = (const float*)d_in[5];
    const float* Ws_v  = (const float*)d_in[6];
    const float* bs_v  = (const float*)d_in[7];
    const float* Wd_v  = (const float*)d_in[8];
    const float* bd_v  = (const float*)d_in[9];
    const float* Wc_p  = (const float*)d_in[10];
    const float* bc_p  = (const float*)d_in[11];
    const float* Ws_p  = (const float*)d_in[12];
    const float* bs_p  = (const float*)d_in[13];
    const float* Wd_p  = (const float*)d_in[14];
    const float* bd_p  = (const float*)d_in[15];
    const float* Wsp   = (const float*)d_in[16];
    const float* bsp   = (const float*)d_in[17];
    const float* W1    = (const float*)d_in[18];
    const float* b1    = (const float*)d_in[19];
    const float* W2    = (const float*)d_in[20];
    const float* b2    = (const float*)d_in[21];
    const float* Wa    = (const float*)d_in[22];
    const float* ba    = (const float*)d_in[23];
    const float* Wf    = (const float*)d_in[24];
    const float* bf    = (const float*)d_in[25];
    float* out = (float*)d_out;

    // workspace: h_v[B][64] | h_p[B][64] | y30[B][30]  = ~2.6 MB
    float* ws  = (float*)d_ws;
    float* h_v = ws;
    float* h_p = ws + (size_t)B_ * 64;
    float* y30 = ws + (size_t)2 * B_ * 64;

    encode_kernel<<<B_, 256, 0, stream>>>(S_V, Wc_v, bc_v, h_v);
    encode_kernel<<<B_, 256, 0, stream>>>(S_P, Wc_p, bc_p, h_p);
    phys_kernel  <<<B_, 256, 0, stream>>>(S_P1, W1, b1, W2, b2, y30);
    head_kernel  <<<B_, 64, 0, stream>>>(pairs, h_v, h_p, y30,
                                         Ws_v, bs_v, Wd_v, bd_v,
                                         Ws_p, bs_p, Wd_p, bd_p,
                                         Wsp, bsp, Wa, ba, Wf, bf, out);
}